// Round 1
// baseline (259.502 us; speedup 1.0000x reference)
//
#include <hip/hip_runtime.h>
#include <hip/hip_bf16.h>
#include <stdint.h>
#include <stddef.h>

#define D_MODEL 2048
#define NOUT    2048      // SLOTS * D_FIELD
#define BATCH   2
#define SEQ     4096
#define M_TOTAL (BATCH*SEQ)   // 8192
#define SLOTS   8
#define D_FIELD 256
#define CHUNK   64
#define NCHUNK  (SEQ/CHUNK)   // 64

typedef __attribute__((ext_vector_type(4))) float  floatx4;
typedef __attribute__((ext_vector_type(8))) __bf16 bf16x8;
typedef __attribute__((ext_vector_type(4))) __bf16 bf16x4;

// ---------------------------------------------------------------------------
// async global -> LDS, 16B per lane. LDS dest must be wave-uniform base + lane*16.
__device__ __forceinline__ void async_copy16(const void* gsrc, void* ldst) {
  __builtin_amdgcn_global_load_lds(
      (__attribute__((address_space(1))) const void*)(uintptr_t)gsrc,
      (__attribute__((address_space(3))) void*)(uintptr_t)ldst,
      16, 0, 0);
}

// ---------------------------------------------------------------------------
// Kernel 1: cast x and W fp32 -> bf16 into workspace. 4 elems / thread.
__global__ void cast_kernel(const float* __restrict__ x,
                            const float* __restrict__ W,
                            __bf16* __restrict__ xb,
                            __bf16* __restrict__ wb) {
  const long long nx = (long long)M_TOTAL * D_MODEL;  // 16777216
  const long long nw = (long long)NOUT * D_MODEL;     // 4194304
  long long base = ((long long)blockIdx.x * blockDim.x + threadIdx.x) * 4;
  if (base < nx) {
    float4 v = *(const float4*)(x + base);
    bf16x4 o;
    o[0] = (__bf16)v.x; o[1] = (__bf16)v.y; o[2] = (__bf16)v.z; o[3] = (__bf16)v.w;
    *(bf16x4*)(xb + base) = o;
  } else {
    long long j = base - nx;
    if (j < nw) {
      float4 v = *(const float4*)(W + j);
      bf16x4 o;
      o[0] = (__bf16)v.x; o[1] = (__bf16)v.y; o[2] = (__bf16)v.z; o[3] = (__bf16)v.w;
      *(bf16x4*)(wb + j) = o;
    }
  }
}

// ---------------------------------------------------------------------------
// Kernel 2: C[M,N] = Xbf16[M,K] * W[N,K]^T + bias   (m97-style gemm_bt)
// 128x128 tile, BK=32, 256 threads (4 waves, 2x2), 4x4 16x16x32 MFMAs per wave.
__global__ __launch_bounds__(256) void gemm_kernel(
    const __bf16* __restrict__ A,   // [M_TOTAL, D_MODEL]
    const __bf16* __restrict__ Bw,  // [NOUT, D_MODEL]
    const float*  __restrict__ bias,// [NOUT]
    float* __restrict__ C) {        // [M_TOTAL, NOUT]
  __shared__ __align__(16) __bf16 sA[128 * 32];
  __shared__ __align__(16) __bf16 sB[128 * 32];

  const int t    = threadIdx.x;
  const int lane = t & 63;
  const int wave = t >> 6;
  const int wM   = wave >> 1;
  const int wN   = wave & 1;
  const int m0   = blockIdx.y * 128;
  const int n0   = blockIdx.x * 128;
  const int K    = D_MODEL;

  // staging coords: thread t covers tile bytes [t*16, t*16+16) of the 128x32 tile
  const int rA   = t >> 2;          // tile row 0..63 (issue 0), +64 (issue 1)
  const int cOff = (t & 3) * 8;     // k-element offset within 32-wide k-tile

  const __bf16* gA0 = A  + (size_t)(m0 + rA) * K + cOff;
  const __bf16* gA1 = gA0 + (size_t)64 * K;
  const __bf16* gB0 = Bw + (size_t)(n0 + rA) * K + cOff;
  const __bf16* gB1 = gB0 + (size_t)64 * K;

  __bf16* lA = sA + t * 8;          // byte offset t*16
  __bf16* lB = sB + t * 8;

  // fragment read offsets (elements): row (lane&15), k-group (lane>>4)*8
  const int frag_off = (lane & 15) * 32 + (lane >> 4) * 8;
  const __bf16* fA = sA + wM * 64 * 32 + frag_off;
  const __bf16* fB = sB + wN * 64 * 32 + frag_off;

  floatx4 acc[4][4] = {};

  for (int kt = 0; kt < K; kt += 32) {
    __syncthreads();
    async_copy16(gA0 + kt, lA);
    async_copy16(gA1 + kt, lA + 2048);   // second 4KB half: rows 64..127
    async_copy16(gB0 + kt, lB);
    async_copy16(gB1 + kt, lB + 2048);
    __syncthreads();                      // compiler emits vmcnt(0) drain here

    bf16x8 af[4], bfr[4];
#pragma unroll
    for (int i = 0; i < 4; ++i) af[i]  = *(const bf16x8*)(fA + i * 16 * 32);
#pragma unroll
    for (int i = 0; i < 4; ++i) bfr[i] = *(const bf16x8*)(fB + i * 16 * 32);

#pragma unroll
    for (int mi = 0; mi < 4; ++mi)
#pragma unroll
      for (int ni = 0; ni < 4; ++ni)
        acc[mi][ni] = __builtin_amdgcn_mfma_f32_16x16x32_bf16(
            af[mi], bfr[ni], acc[mi][ni], 0, 0, 0);
  }

  // epilogue: C/D layout col=lane&15, row=(lane>>4)*4+reg
  const int mBase = m0 + wM * 64 + (lane >> 4) * 4;
  const int nBase = n0 + wN * 64 + (lane & 15);
#pragma unroll
  for (int ni = 0; ni < 4; ++ni) {
    const int n = nBase + ni * 16;
    const float bv = bias[n];
#pragma unroll
    for (int mi = 0; mi < 4; ++mi) {
      const int m = mBase + mi * 16;
#pragma unroll
      for (int r = 0; r < 4; ++r) {
        C[(size_t)(m + r) * NOUT + n] = acc[mi][ni][r] + bv;
      }
    }
  }
}

// ---------------------------------------------------------------------------
// Kernel 3 (P1): per-chunk carries. thread = (b, chunk j, column c).
// carry[b][j][c] = scan over chunk with zero init, end state.
__global__ void scan_p1(const float* __restrict__ U,
                        const float* __restrict__ alphas,
                        float* __restrict__ carry) {
  const int idx  = blockIdx.x * blockDim.x + threadIdx.x;  // [0, 2*64*2048)
  const int c    = idx & 2047;
  const int rest = idx >> 11;
  const int j    = rest & (NCHUNK - 1);
  const int b    = rest >> 6;
  const float alpha = alphas[c >> 8];
  const float* p = U + ((size_t)(b * SEQ + j * CHUNK) * NOUT) + c;
  float s = 0.f;
#pragma unroll 8
  for (int tt = 0; tt < CHUNK; ++tt)
    s = alpha * s + p[(size_t)tt * NOUT];
  carry[idx] = s;
}

// Kernel 4 (P2): scan carries across chunks per column with multiplier alpha^CHUNK.
__global__ void scan_p2(const float* __restrict__ alphas,
                        float* __restrict__ carry) {
  const int idx = blockIdx.x * blockDim.x + threadIdx.x;   // [0, 2*2048)
  const int c   = idx & 2047;
  const int b   = idx >> 11;
  const float alpha = alphas[c >> 8];
  float a64 = alpha;
#pragma unroll
  for (int i = 0; i < 6; ++i) a64 = a64 * a64;   // alpha^64
  float* p = carry + (size_t)b * NCHUNK * NOUT + c;
  float s = 0.f;
  for (int j = 0; j < NCHUNK; ++j) {
    s = a64 * s + p[(size_t)j * NOUT];
    p[(size_t)j * NOUT] = s;
  }
}

// Kernel 5 (P3): apply carry-in and rewrite chunk in place.
__global__ void scan_p3(float* __restrict__ U,
                        const float* __restrict__ alphas,
                        const float* __restrict__ carry) {
  const int idx  = blockIdx.x * blockDim.x + threadIdx.x;
  const int c    = idx & 2047;
  const int rest = idx >> 11;
  const int j    = rest & (NCHUNK - 1);
  const int b    = rest >> 6;
  const float alpha = alphas[c >> 8];
  float s = (j == 0) ? 0.f : carry[((size_t)(b * NCHUNK + (j - 1))) * 1 * NOUT + c - c + ((size_t)(b * NCHUNK + (j - 1))) * 0 + c + ((size_t)(b * NCHUNK + (j - 1)) * NOUT - ((size_t)(b * NCHUNK + (j - 1))) * NOUT)];
  // (clean form below; keep simple:)
  if (j != 0) s = carry[(size_t)(b * NCHUNK + (j - 1)) * NOUT + c];
  float* p = U + ((size_t)(b * SEQ + j * CHUNK) * NOUT) + c;
#pragma unroll 8
  for (int tt = 0; tt < CHUNK; ++tt) {
    const float v = alpha * s + p[(size_t)tt * NOUT];
    p[(size_t)tt * NOUT] = v;
    s = v;
  }
}

// ---------------------------------------------------------------------------
extern "C" void kernel_launch(void* const* d_in, const int* in_sizes, int n_in,
                              void* d_out, int out_size, void* d_ws, size_t ws_size,
                              hipStream_t stream) {
  const float* x      = (const float*)d_in[0];
  const float* W      = (const float*)d_in[1];
  const float* bias   = (const float*)d_in[2];
  const float* alphas = (const float*)d_in[3];
  float* out = (float*)d_out;

  // workspace layout (bytes): xb 33,554,432 | wb 8,388,608 | carry 1,048,576
  __bf16* xb   = (__bf16*)d_ws;
  __bf16* wb   = (__bf16*)((char*)d_ws + (size_t)M_TOTAL * D_MODEL * 2);
  float* carry = (float*)((char*)d_ws + (size_t)M_TOTAL * D_MODEL * 2
                                       + (size_t)NOUT * D_MODEL * 2);

  // 1) cast fp32 -> bf16
  {
    const long long total = ((long long)M_TOTAL * D_MODEL + (long long)NOUT * D_MODEL) / 4;
    const int blocks = (int)((total + 255) / 256);  // 20480
    cast_kernel<<<blocks, 256, 0, stream>>>(x, W, xb, wb);
  }
  // 2) projection GEMM + bias -> d_out (updates)
  {
    dim3 grid(NOUT / 128, M_TOTAL / 128);  // (16, 64)
    gemm_kernel<<<grid, 256, 0, stream>>>(xb, wb, bias, out);
  }
  // 3) chunked EMA scan, in place on d_out
  scan_p1<<<(BATCH * NCHUNK * NOUT) / 256, 256, 0, stream>>>(out, alphas, carry);
  scan_p2<<<(BATCH * NOUT) / 256, 256, 0, stream>>>(alphas, carry);
  scan_p3<<<(BATCH * NCHUNK * NOUT) / 256, 256, 0, stream>>>(out, alphas, carry);
}

// Round 2
// 229.900 us; speedup vs baseline: 1.1288x; 1.1288x over previous
//
#include <hip/hip_runtime.h>
#include <hip/hip_bf16.h>
#include <stdint.h>
#include <stddef.h>

#define D_MODEL 2048
#define NOUT    2048      // SLOTS * D_FIELD
#define BATCH   2
#define SEQ     4096
#define M_TOTAL (BATCH*SEQ)   // 8192
#define SLOTS   8
#define D_FIELD 256
#define CHUNK   64
#define NCHUNK  (SEQ/CHUNK)   // 64

typedef __attribute__((ext_vector_type(4))) float  floatx4;
typedef __attribute__((ext_vector_type(8))) __bf16 bf16x8;
typedef __attribute__((ext_vector_type(4))) __bf16 bf16x4;

// ---------------------------------------------------------------------------
// async global -> LDS, 16B per lane. LDS dest must be wave-uniform base + lane*16.
__device__ __forceinline__ void async_copy16(const void* gsrc, void* ldst) {
  __builtin_amdgcn_global_load_lds(
      (__attribute__((address_space(1))) const void*)(uintptr_t)gsrc,
      (__attribute__((address_space(3))) void*)(uintptr_t)ldst,
      16, 0, 0);
}

// ---------------------------------------------------------------------------
// Kernel 1: cast x and W fp32 -> bf16 into workspace. 4 elems / thread.
__global__ void cast_kernel(const float* __restrict__ x,
                            const float* __restrict__ W,
                            __bf16* __restrict__ xb,
                            __bf16* __restrict__ wb) {
  const long long nx = (long long)M_TOTAL * D_MODEL;  // 16777216
  const long long nw = (long long)NOUT * D_MODEL;     // 4194304
  long long base = ((long long)blockIdx.x * blockDim.x + threadIdx.x) * 4;
  if (base < nx) {
    float4 v = *(const float4*)(x + base);
    bf16x4 o;
    o[0] = (__bf16)v.x; o[1] = (__bf16)v.y; o[2] = (__bf16)v.z; o[3] = (__bf16)v.w;
    *(bf16x4*)(xb + base) = o;
  } else {
    long long j = base - nx;
    if (j < nw) {
      float4 v = *(const float4*)(W + j);
      bf16x4 o;
      o[0] = (__bf16)v.x; o[1] = (__bf16)v.y; o[2] = (__bf16)v.z; o[3] = (__bf16)v.w;
      *(bf16x4*)(wb + j) = o;
    }
  }
}

// ---------------------------------------------------------------------------
// Kernel 2: C[M,N] = Xbf16[M,K] * W[N,K]^T + bias, fused per-chunk carry (scan P1).
// 128x128 tile, BK=64, XOR-swizzled LDS (slot = kgroup ^ (row&7), row stride 64
// elems = 128 B -> fragment reads hit 8 distinct bank-bases x2 = conflict-free).
// 256 threads (4 waves, 2x2 of 64x64), 4x4 16x16x32 MFMAs per wave per k-sub.
__global__ __launch_bounds__(256) void gemm_scan_kernel(
    const __bf16* __restrict__ A,    // [M_TOTAL, D_MODEL]
    const __bf16* __restrict__ Bw,   // [NOUT, D_MODEL]
    const float*  __restrict__ bias, // [NOUT]
    const float*  __restrict__ alphas,
    float* __restrict__ C,           // [M_TOTAL, NOUT]
    float* __restrict__ carry) {     // [BATCH, NCHUNK, NOUT]
  __shared__ __align__(16) __bf16 sA[128 * 64];
  __shared__ __align__(16) __bf16 sB[128 * 64];

  const int t    = threadIdx.x;
  const int lane = t & 63;
  const int wave = t >> 6;
  const int wM   = wave >> 1;
  const int wN   = wave & 1;
  const int m0   = blockIdx.y * 128;
  const int n0   = blockIdx.x * 128;
  const int K    = D_MODEL;

  // staging: thread t covers LDS row r0 = t>>3 (+32 per issue), slot t&7.
  // swizzle: LDS slot s of row r holds k-group g = s ^ (r&7); so this thread
  // loads global k-group g = (t&7) ^ (r0&7). r0&7 invariant across issues (+32).
  const int r0 = t >> 3;
  const int g  = (t & 7) ^ (r0 & 7);
  const __bf16* gA = A  + (size_t)(m0 + r0) * K + g * 8;
  const __bf16* gB = Bw + (size_t)(n0 + r0) * K + g * 8;
  __bf16* lA = sA + t * 8;   // byte offset t*16, wave-contiguous per issue
  __bf16* lB = sB + t * 8;

  const int q = lane >> 4;       // quad 0..3
  const int L = lane & 15;       // row-in-16
  const int xorL = L & 7;
  const __bf16* fA = sA + (wM * 64 + L) * 64;
  const __bf16* fB = sB + (wN * 64 + L) * 64;

  floatx4 acc[4][4] = {};

  for (int kt = 0; kt < K; kt += 64) {
    __syncthreads();
#pragma unroll
    for (int i = 0; i < 4; ++i) {
      async_copy16(gA + kt + (size_t)i * 32 * K, lA + i * 2048);
      async_copy16(gB + kt + (size_t)i * 32 * K, lB + i * 2048);
    }
    __syncthreads();   // vmcnt(0) drain
#pragma unroll
    for (int kk = 0; kk < 2; ++kk) {
      const int slot = (((kk * 4 + q) ^ xorL)) * 8;
      bf16x8 af[4], bfr[4];
#pragma unroll
      for (int mi = 0; mi < 4; ++mi) af[mi]  = *(const bf16x8*)(fA + mi * 1024 + slot);
#pragma unroll
      for (int ni = 0; ni < 4; ++ni) bfr[ni] = *(const bf16x8*)(fB + ni * 1024 + slot);
#pragma unroll
      for (int mi = 0; mi < 4; ++mi)
#pragma unroll
        for (int ni = 0; ni < 4; ++ni)
          acc[mi][ni] = __builtin_amdgcn_mfma_f32_16x16x32_bf16(
              af[mi], bfr[ni], acc[mi][ni], 0, 0, 0);
    }
  }

  // ---- epilogue: write C (+bias) and fused per-chunk carry ----
  // C/D layout: col = L, row = q*4 + reg. Wave (wM) owns chunk rows 0..63:
  // local row rho = q*4 + mi*16 + r. carry = sum_rho alpha^(63-rho) * u_rho.
  const int mBase = m0 + wM * 64 + q * 4;
  const int nBase = n0 + wN * 64 + L;
  const float alpha = alphas[(n0 + wN * 64) >> 8];   // slot const per 64-col stripe
  const float a4  = (alpha * alpha) * (alpha * alpha);
  const float a16 = (a4 * a4) * (a4 * a4);
  float aq = 1.f;                       // alpha^(12-4q)
#pragma unroll
  for (int i = 0; i < 3; ++i) if (i < 3 - q) aq *= a4;
  const int gm0 = m0 + wM * 64;
  const int bb  = gm0 >> 12;            // / SEQ
  const int jj  = (gm0 & (SEQ - 1)) >> 6;

#pragma unroll
  for (int ni = 0; ni < 4; ++ni) {
    const int n = nBase + ni * 16;
    const float bv = bias[n];
    float tmi[4];
#pragma unroll
    for (int mi = 0; mi < 4; ++mi) {
      const int m = mBase + mi * 16;
      float u[4];
#pragma unroll
      for (int r = 0; r < 4; ++r) {
        u[r] = acc[mi][ni][r] + bv;
        C[(size_t)(m + r) * NOUT + n] = u[r];
      }
      // Horner over r ascending: sum_r alpha^(3-r) u_r
      tmi[mi] = ((u[0] * alpha + u[1]) * alpha + u[2]) * alpha + u[3];
    }
    float s = ((tmi[0] * a16 + tmi[1]) * a16 + tmi[2]) * a16 + tmi[3];
    s *= aq;
    s += __shfl_xor(s, 16, 64);
    s += __shfl_xor(s, 32, 64);
    if (q == 0)
      carry[(size_t)(bb * NCHUNK + jj) * NOUT + n] = s;
  }
}

// ---------------------------------------------------------------------------
// Kernel 3 (P2): scan carries across chunks per column, multiplier alpha^CHUNK.
// Loads pipelined into registers first (independent), then serial combine.
__global__ void scan_p2(const float* __restrict__ alphas,
                        float* __restrict__ carry) {
  const int idx = blockIdx.x * blockDim.x + threadIdx.x;   // [0, 2*2048)
  const int c   = idx & (NOUT - 1);
  const int b   = idx >> 11;
  const float alpha = alphas[c >> 8];
  float a64 = alpha;
#pragma unroll
  for (int i = 0; i < 6; ++i) a64 = a64 * a64;   // alpha^64
  float* p = carry + (size_t)b * NCHUNK * NOUT + c;
  float v[NCHUNK];
#pragma unroll
  for (int j = 0; j < NCHUNK; ++j) v[j] = p[(size_t)j * NOUT];
  float s = 0.f;
#pragma unroll
  for (int j = 0; j < NCHUNK; ++j) {
    s = a64 * s + v[j];
    p[(size_t)j * NOUT] = s;
  }
}

// ---------------------------------------------------------------------------
// Kernel 4 (P3): apply carry-in, rewrite chunk in place. 4 cols (float4)/thread.
__global__ void scan_p3(float* __restrict__ U,
                        const float* __restrict__ alphas,
                        const float* __restrict__ carry) {
  const int idx = blockIdx.x * blockDim.x + threadIdx.x;  // [0, 2*64*512)
  const int c   = (idx & 511) * 4;
  const int j   = (idx >> 9) & (NCHUNK - 1);
  const int b   = idx >> 15;
  const float alpha = alphas[c >> 8];
  floatx4 s;
  if (j == 0) {
    s = 0.f;
  } else {
    s = *(const floatx4*)(carry + (size_t)(b * NCHUNK + (j - 1)) * NOUT + c);
  }
  float* p = U + ((size_t)(b * SEQ + j * CHUNK) * NOUT) + c;
#pragma unroll 8
  for (int tt = 0; tt < CHUNK; ++tt) {
    floatx4 u = *(const floatx4*)(p + (size_t)tt * NOUT);
    floatx4 v = alpha * s + u;
    *(floatx4*)(p + (size_t)tt * NOUT) = v;
    s = v;
  }
}

// ---------------------------------------------------------------------------
extern "C" void kernel_launch(void* const* d_in, const int* in_sizes, int n_in,
                              void* d_out, int out_size, void* d_ws, size_t ws_size,
                              hipStream_t stream) {
  const float* x      = (const float*)d_in[0];
  const float* W      = (const float*)d_in[1];
  const float* bias   = (const float*)d_in[2];
  const float* alphas = (const float*)d_in[3];
  float* out = (float*)d_out;

  // workspace layout (bytes): xb 33,554,432 | wb 8,388,608 | carry 1,048,576
  __bf16* xb   = (__bf16*)d_ws;
  __bf16* wb   = (__bf16*)((char*)d_ws + (size_t)M_TOTAL * D_MODEL * 2);
  float* carry = (float*)((char*)d_ws + (size_t)M_TOTAL * D_MODEL * 2
                                       + (size_t)NOUT * D_MODEL * 2);

  // 1) cast fp32 -> bf16
  {
    const long long total = ((long long)M_TOTAL * D_MODEL + (long long)NOUT * D_MODEL) / 4;
    const int blocks = (int)((total + 255) / 256);  // 20480
    cast_kernel<<<blocks, 256, 0, stream>>>(x, W, xb, wb);
  }
  // 2) projection GEMM + bias -> d_out, fused per-chunk carries -> ws
  {
    dim3 grid(NOUT / 128, M_TOTAL / 128);  // (16, 64)
    gemm_scan_kernel<<<grid, 256, 0, stream>>>(xb, wb, bias, alphas, out, carry);
  }
  // 3) chunk-carry scan + apply, in place on d_out
  scan_p2<<<(BATCH * NOUT) / 256, 256, 0, stream>>>(alphas, carry);
  scan_p3<<<(BATCH * NCHUNK * NOUT / 4) / 256, 256, 0, stream>>>(out, alphas, carry);
}

// Round 3
// 229.280 us; speedup vs baseline: 1.1318x; 1.0027x over previous
//
#include <hip/hip_runtime.h>
#include <hip/hip_bf16.h>
#include <stdint.h>
#include <stddef.h>

#define D_MODEL 2048
#define NOUT    2048      // SLOTS * D_FIELD
#define BATCH   2
#define SEQ     4096
#define M_TOTAL (BATCH*SEQ)   // 8192
#define SLOTS   8
#define D_FIELD 256
#define CHUNK   64
#define NCHUNK  (SEQ/CHUNK)   // 64

typedef __attribute__((ext_vector_type(4))) float  floatx4;
typedef __attribute__((ext_vector_type(8))) __bf16 bf16x8;
typedef __attribute__((ext_vector_type(4))) __bf16 bf16x4;

// ---------------------------------------------------------------------------
// async global -> LDS, 16B per lane. LDS dest must be wave-uniform base + lane*16.
__device__ __forceinline__ void async_copy16(const void* gsrc, void* ldst) {
  __builtin_amdgcn_global_load_lds(
      (__attribute__((address_space(1))) const void*)(uintptr_t)gsrc,
      (__attribute__((address_space(3))) void*)(uintptr_t)ldst,
      16, 0, 0);
}

// ---------------------------------------------------------------------------
// Kernel 1: cast x and W fp32 -> bf16 into workspace. 4 elems / thread.
__global__ void cast_kernel(const float* __restrict__ x,
                            const float* __restrict__ W,
                            __bf16* __restrict__ xb,
                            __bf16* __restrict__ wb) {
  const long long nx = (long long)M_TOTAL * D_MODEL;  // 16777216
  const long long nw = (long long)NOUT * D_MODEL;     // 4194304
  long long base = ((long long)blockIdx.x * blockDim.x + threadIdx.x) * 4;
  if (base < nx) {
    float4 v = *(const float4*)(x + base);
    bf16x4 o;
    o[0] = (__bf16)v.x; o[1] = (__bf16)v.y; o[2] = (__bf16)v.z; o[3] = (__bf16)v.w;
    *(bf16x4*)(xb + base) = o;
  } else {
    long long j = base - nx;
    if (j < nw) {
      float4 v = *(const float4*)(W + j);
      bf16x4 o;
      o[0] = (__bf16)v.x; o[1] = (__bf16)v.y; o[2] = (__bf16)v.z; o[3] = (__bf16)v.w;
      *(bf16x4*)(wb + j) = o;
    }
  }
}

// ---------------------------------------------------------------------------
// Kernel 2: C[M,N] = Xbf16[M,K] * W[N,K]^T + bias, fused per-chunk carry (scan P1).
// 128x128 tile, BK=64, XOR-swizzled LDS (conflict-free, verified R2: 0 conflicts).
// Grid is (m-blocks fast, n-blocks slow): with round-robin block->XCD dispatch,
// the 16 blocks sharing an A-tile stride 64 = 0 mod 8 -> same XCD (A fetched ~1x);
// B-tiles replicate across XCDs (8.4MB * 8 = 67MB) — net FETCH down vs transpose.
__global__ __launch_bounds__(256) void gemm_scan_kernel(
    const __bf16* __restrict__ A,    // [M_TOTAL, D_MODEL]
    const __bf16* __restrict__ Bw,   // [NOUT, D_MODEL]
    const float*  __restrict__ bias, // [NOUT]
    const float*  __restrict__ alphas,
    float* __restrict__ C,           // [M_TOTAL, NOUT]
    float* __restrict__ carry) {     // [BATCH, NCHUNK, NOUT]
  __shared__ __align__(16) __bf16 sA[128 * 64];
  __shared__ __align__(16) __bf16 sB[128 * 64];

  const int t    = threadIdx.x;
  const int lane = t & 63;
  const int wave = t >> 6;
  const int wM   = wave >> 1;
  const int wN   = wave & 1;
  const int m0   = blockIdx.x * 128;   // m fast -> A-tile pinned per XCD
  const int n0   = blockIdx.y * 128;
  const int K    = D_MODEL;

  // staging: thread t covers LDS row r0 = t>>3 (+32 per issue), slot t&7.
  // swizzle: LDS slot s of row r holds k-group g = s ^ (r&7).
  const int r0 = t >> 3;
  const int g  = (t & 7) ^ (r0 & 7);
  const __bf16* gA = A  + (size_t)(m0 + r0) * K + g * 8;
  const __bf16* gB = Bw + (size_t)(n0 + r0) * K + g * 8;
  __bf16* lA = sA + t * 8;
  __bf16* lB = sB + t * 8;

  const int q = lane >> 4;       // quad 0..3
  const int L = lane & 15;       // row-in-16
  const int xorL = L & 7;
  const __bf16* fA = sA + (wM * 64 + L) * 64;
  const __bf16* fB = sB + (wN * 64 + L) * 64;

  floatx4 acc[4][4] = {};

  for (int kt = 0; kt < K; kt += 64) {
    __syncthreads();
#pragma unroll
    for (int i = 0; i < 4; ++i) {
      async_copy16(gA + kt + (size_t)i * 32 * K, lA + i * 2048);
      async_copy16(gB + kt + (size_t)i * 32 * K, lB + i * 2048);
    }
    __syncthreads();   // vmcnt(0) drain
#pragma unroll
    for (int kk = 0; kk < 2; ++kk) {
      const int slot = (((kk * 4 + q) ^ xorL)) * 8;
      bf16x8 af[4], bfr[4];
#pragma unroll
      for (int mi = 0; mi < 4; ++mi) af[mi]  = *(const bf16x8*)(fA + mi * 1024 + slot);
#pragma unroll
      for (int ni = 0; ni < 4; ++ni) bfr[ni] = *(const bf16x8*)(fB + ni * 1024 + slot);
#pragma unroll
      for (int mi = 0; mi < 4; ++mi)
#pragma unroll
        for (int ni = 0; ni < 4; ++ni)
          acc[mi][ni] = __builtin_amdgcn_mfma_f32_16x16x32_bf16(
              af[mi], bfr[ni], acc[mi][ni], 0, 0, 0);
    }
  }

  // ---- epilogue: write C (+bias) and fused per-chunk carry ----
  // C/D layout: col = L, row = q*4 + reg. Wave row-block = one 64-row chunk.
  const int mBase = m0 + wM * 64 + q * 4;
  const int nBase = n0 + wN * 64 + L;
  const float alpha = alphas[(n0 + wN * 64) >> 8];
  const float a4  = (alpha * alpha) * (alpha * alpha);
  const float a16 = (a4 * a4) * (a4 * a4);
  float aq = 1.f;                       // alpha^(12-4q)
#pragma unroll
  for (int i = 0; i < 3; ++i) if (i < 3 - q) aq *= a4;
  const int gm0 = m0 + wM * 64;
  const int bb  = gm0 >> 12;            // / SEQ
  const int jj  = (gm0 & (SEQ - 1)) >> 6;

#pragma unroll
  for (int ni = 0; ni < 4; ++ni) {
    const int n = nBase + ni * 16;
    const float bv = bias[n];
    float tmi[4];
#pragma unroll
    for (int mi = 0; mi < 4; ++mi) {
      const int m = mBase + mi * 16;
      float u[4];
#pragma unroll
      for (int r = 0; r < 4; ++r) {
        u[r] = acc[mi][ni][r] + bv;
        C[(size_t)(m + r) * NOUT + n] = u[r];
      }
      tmi[mi] = ((u[0] * alpha + u[1]) * alpha + u[2]) * alpha + u[3];
    }
    float s = ((tmi[0] * a16 + tmi[1]) * a16 + tmi[2]) * a16 + tmi[3];
    s *= aq;
    s += __shfl_xor(s, 16, 64);
    s += __shfl_xor(s, 32, 64);
    if (q == 0)
      carry[(size_t)(bb * NCHUNK + jj) * NOUT + n] = s;
  }
}

// ---------------------------------------------------------------------------
// Kernel 3 (P2): scan carries across chunks per column, multiplier alpha^CHUNK.
// Wave-parallel Kogge-Stone: one wave per (b,c); lane j = chunk j. 6 shfl steps.
// R2 post-mortem: register-array version spilled (VGPR=64) and ran on 16 CUs
// -> 108 us. This version: 4096 waves, no spill, no serial chain.
__global__ __launch_bounds__(256) void scan_p2(const float* __restrict__ alphas,
                                               float* __restrict__ carry) {
  const int w    = blockIdx.x * 4 + (threadIdx.x >> 6);  // wave id [0, 4096)
  const int lane = threadIdx.x & 63;                     // chunk index j
  const int c    = w & (NOUT - 1);
  const int b    = w >> 11;
  const float alpha = alphas[c >> 8];
  float a64 = alpha;
#pragma unroll
  for (int i = 0; i < 6; ++i) a64 = a64 * a64;   // alpha^64

  float* p = carry + ((size_t)(b * NCHUNK + lane)) * NOUT + c;
  float v = *p;
  float m = a64;
#pragma unroll
  for (int step = 1; step < 64; step <<= 1) {
    float o = __shfl_up(v, step, 64);
    if (lane >= step) v += m * o;
    m = m * m;
  }
  *p = v;
}

// ---------------------------------------------------------------------------
// Kernel 4 (P3): apply carry-in, rewrite chunk in place. 4 cols (float4)/thread.
__global__ void scan_p3(float* __restrict__ U,
                        const float* __restrict__ alphas,
                        const float* __restrict__ carry) {
  const int idx = blockIdx.x * blockDim.x + threadIdx.x;  // [0, 2*64*512)
  const int c   = (idx & 511) * 4;
  const int j   = (idx >> 9) & (NCHUNK - 1);
  const int b   = idx >> 15;
  const float alpha = alphas[c >> 8];
  floatx4 s;
  if (j == 0) {
    s = 0.f;
  } else {
    s = *(const floatx4*)(carry + (size_t)(b * NCHUNK + (j - 1)) * NOUT + c);
  }
  float* p = U + ((size_t)(b * SEQ + j * CHUNK) * NOUT) + c;
#pragma unroll 8
  for (int tt = 0; tt < CHUNK; ++tt) {
    floatx4 u = *(const floatx4*)(p + (size_t)tt * NOUT);
    floatx4 v = alpha * s + u;
    *(floatx4*)(p + (size_t)tt * NOUT) = v;
    s = v;
  }
}

// ---------------------------------------------------------------------------
extern "C" void kernel_launch(void* const* d_in, const int* in_sizes, int n_in,
                              void* d_out, int out_size, void* d_ws, size_t ws_size,
                              hipStream_t stream) {
  const float* x      = (const float*)d_in[0];
  const float* W      = (const float*)d_in[1];
  const float* bias   = (const float*)d_in[2];
  const float* alphas = (const float*)d_in[3];
  float* out = (float*)d_out;

  // workspace layout (bytes): xb 33,554,432 | wb 8,388,608 | carry 1,048,576
  __bf16* xb   = (__bf16*)d_ws;
  __bf16* wb   = (__bf16*)((char*)d_ws + (size_t)M_TOTAL * D_MODEL * 2);
  float* carry = (float*)((char*)d_ws + (size_t)M_TOTAL * D_MODEL * 2
                                       + (size_t)NOUT * D_MODEL * 2);

  // 1) cast fp32 -> bf16
  {
    const long long total = ((long long)M_TOTAL * D_MODEL + (long long)NOUT * D_MODEL) / 4;
    const int blocks = (int)((total + 255) / 256);  // 20480
    cast_kernel<<<blocks, 256, 0, stream>>>(x, W, xb, wb);
  }
  // 2) projection GEMM + bias -> d_out, fused per-chunk carries -> ws
  {
    dim3 grid(M_TOTAL / 128, NOUT / 128);  // (64, 16) — m fast for XCD locality
    gemm_scan_kernel<<<grid, 256, 0, stream>>>(xb, wb, bias, alphas, out, carry);
  }
  // 3) chunk-carry scan + apply, in place on d_out
  scan_p2<<<(BATCH * NOUT) / 4, 256, 0, stream>>>(alphas, carry);
  scan_p3<<<(BATCH * NCHUNK * NOUT / 4) / 256, 256, 0, stream>>>(out, alphas, carry);
}